// Round 7
// baseline (44.418 us; speedup 1.0000x reference)
//
#include <hip/hip_runtime.h>
#include <math.h>
#include <stdint.h>

#define BN 2048
#define KF 512
#define OF 512
#define NH 8
#define DD 64

typedef __attribute__((ext_vector_type(8))) short short8;
typedef __attribute__((ext_vector_type(4))) float f32x4;
typedef unsigned short ushortT;

static __device__ __forceinline__ ushortT f2bf(float f) {
  unsigned u = __float_as_uint(f);
  u += 0x7fffu + ((u >> 16) & 1u);   // RNE
  return (ushortT)(u >> 16);
}
static __device__ __forceinline__ float bf2f(ushortT b) {
  return __uint_as_float(((unsigned)b) << 16);
}

// ============ Kernel A: adj bitpack + MFMA split-bf16 GEMM + score tables ====
// grid (NH, BN/32) = 512 blocks, 256 threads.  (unchanged from R6)
__global__ __launch_bounds__(256, 2) void k_main(
    const float* __restrict__ x, const int* __restrict__ adj,
    const float* __restrict__ W, const float* __restrict__ Wb,
    const float* __restrict__ av,
    ushortT* __restrict__ hbT, float* __restrict__ E12s, float* __restrict__ E12d,
    uint8_t* __restrict__ adjB) {
  __shared__ __align__(16) uint8_t smem[24576];
  __shared__ float sredS[2][32], sredD[2][32];

  const int t    = threadIdx.x;
  const int hh   = blockIdx.x;
  const int i0   = blockIdx.y * 32;
  const int b    = hh * 64 + blockIdx.y;
  const int lane = t & 63;
  const int wv   = t >> 6;
  const int mt   = wv & 1;
  const int nt   = wv >> 1;
  const int l15  = lane & 15;
  const int lq   = lane >> 4;

  {
    const int gtid = b * 256 + t;
#pragma unroll
    for (int it = 0; it < 4; ++it) {
      const int bidx = gtid + it * (512 * 256);
      const int4 v0 = *(const int4*)(adj + (size_t)bidx * 8);
      const int4 v1 = *(const int4*)(adj + (size_t)bidx * 8 + 4);
      unsigned m = (v0.x ? 1u : 0u) | (v0.y ? 2u : 0u) | (v0.z ? 4u : 0u) | (v0.w ? 8u : 0u)
                 | (v1.x ? 16u : 0u) | (v1.y ? 32u : 0u) | (v1.z ? 64u : 0u) | (v1.w ? 128u : 0u);
      adjB[bidx] = (uint8_t)m;
    }
  }

  ushortT* sAh = (ushortT*)smem;
  ushortT* sAl = sAh + 32 * 64;
  ushortT* sBh = sAl + 32 * 64;
  ushortT* sBl = sBh + 64 * 64;

  f32x4 acc[2] = {};
  const int srow = t >> 3, ss = t & 7;
  int4 aHi, aLo, bHi[2], bLo[2];

  {
    const float* xs = x + (size_t)(i0 + srow) * KF + ss * 8;
    float v[8];
    *(float4*)&v[0] = *(const float4*)xs;
    *(float4*)&v[4] = *(const float4*)(xs + 4);
    ushortT hi8[8], lo8[8];
#pragma unroll
    for (int i = 0; i < 8; ++i) { hi8[i] = f2bf(v[i]); lo8[i] = f2bf(v[i] - bf2f(hi8[i])); }
    aHi = *(const int4*)hi8; aLo = *(const int4*)lo8;
#pragma unroll
    for (int rep = 0; rep < 2; ++rep) {
      const int S = t + rep * 256, rw = S >> 3, s2 = S & 7;
      const float* wsrc = W + (size_t)(hh * 64 + rw) * KF + s2 * 8;
      float wv8[8];
      *(float4*)&wv8[0] = *(const float4*)wsrc;
      *(float4*)&wv8[4] = *(const float4*)(wsrc + 4);
      ushortT wh8[8], wl8[8];
#pragma unroll
      for (int i = 0; i < 8; ++i) { wh8[i] = f2bf(wv8[i]); wl8[i] = f2bf(wv8[i] - bf2f(wh8[i])); }
      bHi[rep] = *(const int4*)wh8; bLo[rep] = *(const int4*)wl8;
    }
  }

  for (int k0 = 0; k0 < 8; ++k0) {
    __syncthreads();
    {
      const int offA = srow * 64 + ((ss ^ (srow & 7)) * 8);
      *(int4*)&sAh[offA] = aHi;
      *(int4*)&sAl[offA] = aLo;
#pragma unroll
      for (int rep = 0; rep < 2; ++rep) {
        const int S = t + rep * 256, rw = S >> 3, s2 = S & 7;
        const int offB = rw * 64 + ((s2 ^ (rw & 7)) * 8);
        *(int4*)&sBh[offB] = bHi[rep];
        *(int4*)&sBl[offB] = bLo[rep];
      }
    }
    __syncthreads();
    if (k0 < 7) {
      const int kc = (k0 + 1) * 64;
      const float* xs = x + (size_t)(i0 + srow) * KF + kc + ss * 8;
      float v[8];
      *(float4*)&v[0] = *(const float4*)xs;
      *(float4*)&v[4] = *(const float4*)(xs + 4);
      ushortT hi8[8], lo8[8];
#pragma unroll
      for (int i = 0; i < 8; ++i) { hi8[i] = f2bf(v[i]); lo8[i] = f2bf(v[i] - bf2f(hi8[i])); }
      aHi = *(const int4*)hi8; aLo = *(const int4*)lo8;
#pragma unroll
      for (int rep = 0; rep < 2; ++rep) {
        const int S = t + rep * 256, rw = S >> 3, s2 = S & 7;
        const float* wsrc = W + (size_t)(hh * 64 + rw) * KF + kc + s2 * 8;
        float wv8[8];
        *(float4*)&wv8[0] = *(const float4*)wsrc;
        *(float4*)&wv8[4] = *(const float4*)(wsrc + 4);
        ushortT wh8[8], wl8[8];
#pragma unroll
        for (int i = 0; i < 8; ++i) { wh8[i] = f2bf(wv8[i]); wl8[i] = f2bf(wv8[i] - bf2f(wh8[i])); }
        bHi[rep] = *(const int4*)wh8; bLo[rep] = *(const int4*)wl8;
      }
    }
#pragma unroll
    for (int kb = 0; kb < 2; ++kb) {
      const int sc = kb * 4 + lq;
      const int arow = mt * 16 + l15;
      const int offA = arow * 64 + ((sc ^ (arow & 7)) * 8);
      const short8 afh = *(const short8*)&sAh[offA];
      const short8 afl = *(const short8*)&sAl[offA];
      const int br0 = nt * 32 + l15;
      const int br1 = br0 + 16;
      const int offB0 = br0 * 64 + ((sc ^ (br0 & 7)) * 8);
      const int offB1 = br1 * 64 + ((sc ^ (br1 & 7)) * 8);
      const short8 bh0 = *(const short8*)&sBh[offB0];
      const short8 bl0 = *(const short8*)&sBl[offB0];
      const short8 bh1 = *(const short8*)&sBh[offB1];
      const short8 bl1 = *(const short8*)&sBl[offB1];
      acc[0] = __builtin_amdgcn_mfma_f32_16x16x32_bf16(afh, bh0, acc[0], 0, 0, 0);
      acc[1] = __builtin_amdgcn_mfma_f32_16x16x32_bf16(afh, bh1, acc[1], 0, 0, 0);
      acc[0] = __builtin_amdgcn_mfma_f32_16x16x32_bf16(afh, bl0, acc[0], 0, 0, 0);
      acc[1] = __builtin_amdgcn_mfma_f32_16x16x32_bf16(afh, bl1, acc[1], 0, 0, 0);
      acc[0] = __builtin_amdgcn_mfma_f32_16x16x32_bf16(afl, bh0, acc[0], 0, 0, 0);
      acc[1] = __builtin_amdgcn_mfma_f32_16x16x32_bf16(afl, bh1, acc[1], 0, 0, 0);
    }
  }

  __syncthreads();
  ushortT* ldsT = (ushortT*)smem;   // [64 f][40]
  float bias2[2], asv[2], adv[2];
#pragma unroll
  for (int bb = 0; bb < 2; ++bb) {
    const int fl = nt * 32 + bb * 16 + l15;
    bias2[bb] = Wb[hh * 64 + fl];
    asv[bb] = av[fl];
    adv[bb] = av[DD + fl];
  }
#pragma unroll
  for (int p = 0; p < 4; ++p) {
    float vs = 0.f, vd = 0.f;
#pragma unroll
    for (int bb = 0; bb < 2; ++bb) {
      const float hv = acc[bb][p] + bias2[bb];
      const ushortT hu = f2bf(hv);
      vs = fmaf(hv, asv[bb], vs);
      vd = fmaf(hv, adv[bb], vd);
      ldsT[(nt * 32 + bb * 16 + l15) * 40 + mt * 16 + lq * 4 + p] = hu;
    }
    vs += __shfl_xor(vs, 1); vs += __shfl_xor(vs, 2);
    vs += __shfl_xor(vs, 4); vs += __shfl_xor(vs, 8);
    vd += __shfl_xor(vd, 1); vd += __shfl_xor(vd, 2);
    vd += __shfl_xor(vd, 4); vd += __shfl_xor(vd, 8);
    if (l15 == 0) {
      sredS[nt][mt * 16 + lq * 4 + p] = vs;
      sredD[nt][mt * 16 + lq * 4 + p] = vd;
    }
  }
  __syncthreads();
  if (t < 32) {
    const float s1 = sredS[0][t] + sredS[1][t];
    const float s2 = sredD[0][t] + sredD[1][t];
    const size_t gi = (size_t)hh * BN + i0 + t;
    float2 sv; sv.x = __expf(s1); sv.y = __expf(0.2f * s1);
    float2 dv; dv.x = __expf(s2); dv.y = __expf(0.2f * s2);
    *(float2*)&E12s[gi * 2] = sv;
    *(float2*)&E12d[gi * 2] = dv;
  }
  {
    const int f = t >> 2, ic = (t & 3) * 8;
    const int4 v = *(const int4*)&ldsT[f * 40 + ic];
    *(int4*)&hbT[(size_t)(hh * 64 + f) * BN + i0 + ic] = v;
  }
}

// ============ Kernel B: barrier-free j-split attention ======================
// grid (NH, BN/32) = 512 blocks, 256 threads = 4 waves.
// Block owns 32 i-rows; wave wv owns j-chunks [wv*8, wv*8+8) (512 j's each).
// Lane (l15,lq) computes w for rows {i0+l15, i0+16+l15}, j = c*64+kb*32+lq*8+e
// == exactly its MFMA A-fragment. No wA/hB LDS, no barriers in the loop.
__global__ __launch_bounds__(256, 2) void k_attn(
    const ushortT* __restrict__ hbT, const uint8_t* __restrict__ adjB,
    const float* __restrict__ E12s, const float* __restrict__ E12d,
    float* __restrict__ out) {
  __shared__ __align__(16) float e12[BN * 2];          // 16 KB {e1d,e2d} pairs
  __shared__ __align__(16) float cbuf[2][2 * 16 * 68]; // 2 bufs x 8704 B
  __shared__ float denP[4][2][16];

  const int t    = threadIdx.x;
  const int hh   = blockIdx.x;
  const int i0   = blockIdx.y * 32;
  const int lane = t & 63;
  const int wv   = t >> 6;
  const int l15  = lane & 15;
  const int lq   = lane >> 4;

  // stage e12d table (linear; reads below are 16-lane broadcast, 2-way conflict)
  {
    const float4* g = (const float4*)(E12d + (size_t)hh * BN * 2);
#pragma unroll
    for (int rep = 0; rep < 4; ++rep)
      ((float4*)e12)[t + rep * 256] = g[t + rep * 256];
  }

  const float2 eiA = *(const float2*)&E12s[2 * ((size_t)hh * BN + i0 + l15)];
  const float2 eiB = *(const float2*)&E12s[2 * ((size_t)hh * BN + i0 + 16 + l15)];

  f32x4 acc0[4] = {};   // rows [i0, i0+16)
  f32x4 acc1[4] = {};   // rows [i0+16, i0+32)
  float den0 = 0.f, den1 = 0.f;

  const uint8_t* arow0 = adjB + (size_t)(i0 + l15) * 256;
  const uint8_t* arow1 = adjB + (size_t)(i0 + 16 + l15) * 256;
  const ushortT* hbase = hbT + (size_t)(hh * 64 + l15) * BN;

  __syncthreads();   // e12 staged

  const int c0 = wv * 8;
  for (int c = c0; c < c0 + 8; ++c) {
    const uint64_t bits0 = *(const uint64_t*)(arow0 + c * 8);
    const uint64_t bits1 = *(const uint64_t*)(arow1 + c * 8);
#pragma unroll
    for (int kb = 0; kb < 2; ++kb) {
      const int j0 = c * 64 + kb * 32 + lq * 8;
      const float* ep = &e12[j0 * 2];
      const float4 r0 = *(const float4*)(ep);
      const float4 r1 = *(const float4*)(ep + 4);
      const float4 r2 = *(const float4*)(ep + 8);
      const float4 r3 = *(const float4*)(ep + 12);
      float d1[8], d2[8];
      d1[0] = r0.x; d2[0] = r0.y; d1[1] = r0.z; d2[1] = r0.w;
      d1[2] = r1.x; d2[2] = r1.y; d1[3] = r1.z; d2[3] = r1.w;
      d1[4] = r2.x; d2[4] = r2.y; d1[5] = r2.z; d2[5] = r2.w;
      d1[6] = r3.x; d2[6] = r3.y; d1[7] = r3.z; d2[7] = r3.w;
      const unsigned bb0 = (unsigned)(bits0 >> ((kb * 4 + lq) * 8)) & 0xffu;
      const unsigned bb1 = (unsigned)(bits1 >> ((kb * 4 + lq) * 8)) & 0xffu;
      short8 af0, af1;
#pragma unroll
      for (int e = 0; e < 8; ++e) {
        float w0 = fmaxf(eiA.x * d1[e], eiA.y * d2[e]);
        w0 = ((bb0 >> e) & 1u) ? w0 : 0.f;
        const ushortT u0 = f2bf(w0);
        af0[e] = (short)u0;
        den0 += bf2f(u0);
        float w1 = fmaxf(eiB.x * d1[e], eiB.y * d2[e]);
        w1 = ((bb1 >> e) & 1u) ? w1 : 0.f;
        const ushortT u1 = f2bf(w1);
        af1[e] = (short)u1;
        den1 += bf2f(u1);
      }
#pragma unroll
      for (int n = 0; n < 4; ++n) {
        const short8 bf = *(const short8*)(hbase + (size_t)(n * 16) * BN + j0);
        acc0[n] = __builtin_amdgcn_mfma_f32_16x16x32_bf16(af0, bf, acc0[n], 0, 0, 0);
        acc1[n] = __builtin_amdgcn_mfma_f32_16x16x32_bf16(af1, bf, acc1[n], 0, 0, 0);
      }
    }
  }

  // wave-local den reduce over lq groups (lanes l15 + 16*lq)
  den0 += __shfl_xor(den0, 16); den0 += __shfl_xor(den0, 32);
  den1 += __shfl_xor(den1, 16); den1 += __shfl_xor(den1, 32);
  if (lq == 0) {
    denP[wv][0][l15] = den0;
    denP[wv][1][l15] = den1;
  }

  // ---- combine tree (3 barriers total) ----
  // C-frag: value (tile, n, p) lives at row lq*4+p, col n*16+l15.
  if (wv >= 2) {
    float* cb = cbuf[wv - 2];
#pragma unroll
    for (int n = 0; n < 4; ++n)
#pragma unroll
      for (int p = 0; p < 4; ++p) {
        cb[(lq * 4 + p) * 68 + n * 16 + l15] = acc0[n][p];
        cb[(16 + lq * 4 + p) * 68 + n * 16 + l15] = acc1[n][p];
      }
  }
  __syncthreads();
  if (wv < 2) {
    const float* cb = cbuf[wv];
#pragma unroll
    for (int n = 0; n < 4; ++n)
#pragma unroll
      for (int p = 0; p < 4; ++p) {
        acc0[n][p] += cb[(lq * 4 + p) * 68 + n * 16 + l15];
        acc1[n][p] += cb[(16 + lq * 4 + p) * 68 + n * 16 + l15];
      }
    if (wv == 1) {
      float* cw = cbuf[1];
#pragma unroll
      for (int n = 0; n < 4; ++n)
#pragma unroll
        for (int p = 0; p < 4; ++p) {
          cw[(lq * 4 + p) * 68 + n * 16 + l15] = acc0[n][p];
          cw[(16 + lq * 4 + p) * 68 + n * 16 + l15] = acc1[n][p];
        }
    }
  }
  __syncthreads();
  if (wv == 0) {
    const float* cb = cbuf[1];
    float dfin0[4], dfin1[4];
#pragma unroll
    for (int p = 0; p < 4; ++p) {
      const int row = lq * 4 + p;
      dfin0[p] = denP[0][0][row] + denP[1][0][row] + denP[2][0][row] + denP[3][0][row];
      dfin1[p] = denP[0][1][row] + denP[1][1][row] + denP[2][1][row] + denP[3][1][row];
      dfin0[p] = 1.f / dfin0[p];
      dfin1[p] = 1.f / dfin1[p];
    }
#pragma unroll
    for (int n = 0; n < 4; ++n)
#pragma unroll
      for (int p = 0; p < 4; ++p) {
        float v0 = acc0[n][p] + cb[(lq * 4 + p) * 68 + n * 16 + l15];
        float v1 = acc1[n][p] + cb[(16 + lq * 4 + p) * 68 + n * 16 + l15];
        v0 *= dfin0[p];
        v1 *= dfin1[p];
        v0 = v0 > 0.f ? v0 : expm1f(v0);
        v1 = v1 > 0.f ? v1 : expm1f(v1);
        out[(size_t)(i0 + lq * 4 + p) * OF + hh * 64 + n * 16 + l15] = v0;
        out[(size_t)(i0 + 16 + lq * 4 + p) * OF + hh * 64 + n * 16 + l15] = v1;
      }
  }
}

extern "C" void kernel_launch(void* const* d_in, const int* in_sizes, int n_in,
                              void* d_out, int out_size, void* d_ws, size_t ws_size,
                              hipStream_t stream) {
  const float* x  = (const float*)d_in[0];
  const int* adj  = (const int*)d_in[1];
  const float* Ww = (const float*)d_in[2];
  const float* Wb = (const float*)d_in[3];
  const float* a  = (const float*)d_in[4];
  float* outp = (float*)d_out;

  uint8_t* p = (uint8_t*)d_ws;
  ushortT* hbT  = (ushortT*)(p + 0x000000);   // 2 MB
  float*   E12d = (float*)  (p + 0x200000);   // 128 KB
  float*   E12s = (float*)  (p + 0x220000);   // 128 KB
  uint8_t* adjB =            p + 0x240000;    // 512 KB

  k_main<<<dim3(NH, BN / 32), 256, 0, stream>>>(x, adj, Ww, Wb, a, hbT, E12s, E12d, adjB);
  k_attn<<<dim3(NH, BN / 32), 256, 0, stream>>>(hbT, adjB, E12s, E12d, outp);
}